// Round 15
// baseline (645.986 us; speedup 1.0000x reference)
//
#include <hip/hip_runtime.h>
#include <hip/hip_fp8.h>
#include <math.h>

#define T_STEPS 4
#define NN 20000
#define EE 160000
#define IND 64
#define DD 128
#define G3 384     // 3*D (GRU gates)
#define QS 512     // q|k|v|skip fused width
#define CAP 48     // padded-CSR capacity (max degree ~24; P(>=48) ~ 1e-25)

typedef _Float16 f16x8 __attribute__((ext_vector_type(8)));
typedef _Float16 half2v __attribute__((ext_vector_type(2)));
typedef float floatx4 __attribute__((ext_vector_type(4)));

// ---------------------------------------------------------------------------
// fp16 / fp8 helpers
// ---------------------------------------------------------------------------
__device__ inline unsigned short f2h_bits(float x) {
  union { _Float16 h; unsigned short s; } u;
  u.h = (_Float16)x;   // v_cvt_f16_f32 (RNE)
  return u.s;
}
__device__ inline float h2f(unsigned short s) {
  union { unsigned short s; _Float16 h; } u;
  u.s = s;
  return (float)u.h;
}
__device__ inline half2v shfl_xor_h2(half2v v, int m) {
  union { half2v h; int i; } u; u.h = v;
  u.i = __shfl_xor(u.i, m);
  return u.h;
}
__device__ inline unsigned char f2fp8(float x) {   // OCP e4m3fn
  return (unsigned char)__hip_cvt_float_to_fp8(x, __HIP_SATFINITE, __HIP_E4M3);
}
__device__ inline _Float16 fp82h(unsigned char b) {
  __half_raw hr = __hip_cvt_fp8_to_halfraw((__hip_fp8_storage_t)b, __HIP_E4M3);
  union { unsigned short s; _Float16 h; } u;
  u.s = hr.x;
  return u.h;
}

// ---------------------------------------------------------------------------
// f16 MFMA GEMM, LDS-staged single-f16 B: C = A x B + bias, fp16 out.
// Block = 512 thr (8 waves) sharing one 128-col group; B (<=32KB) staged
// once (r9-proven). 32-row wave tile; DO NOT enlarge (r6 spill).
// ---------------------------------------------------------------------------
__global__ __launch_bounds__(512) void gemm_f16(
    const unsigned short* __restrict__ A,
    const unsigned short* __restrict__ Bp, const float* __restrict__ bias,
    unsigned short* __restrict__ Cb, int M, int N, int K)
{
  __shared__ unsigned short Bs[16384];   // 32 KB (max ktiles=4)
  const int ngroups = N >> 7;
  const int mtiles = M >> 5;
  const int ng = blockIdx.x % ngroups;
  const int mb = blockIdx.x / ngroups;
  const int ktiles = K >> 5;
  const int tid = threadIdx.x;
  const unsigned short* Bsrc = Bp + (size_t)ng * 8 * ktiles * 512;
  const int nchunk = ktiles * 8 * 64;   // 16B chunks
  for (int i = tid; i < nchunk; i += 512)
    *(uint4*)&Bs[i * 8] = *(const uint4*)&Bsrc[i * 8];
  __syncthreads();
  const int w = tid >> 6;
  const int lane = tid & 63;
  const int mw = mb * 8 + w;
  if (mw >= mtiles) return;
  const int r = lane & 15, quad = lane >> 4;
  const unsigned short* a0 = A + (size_t)(mw * 32 + r) * K + quad * 8;
  const unsigned short* a1 = a0 + (size_t)16 * K;
  floatx4 acc[2][8];
#pragma unroll
  for (int m = 0; m < 2; ++m)
#pragma unroll
    for (int nt = 0; nt < 8; ++nt) acc[m][nt] = (floatx4){0.f, 0.f, 0.f, 0.f};
  for (int kt = 0; kt < ktiles; ++kt) {
    f16x8 af0 = *(const f16x8*)(a0 + kt * 32);
    f16x8 af1 = *(const f16x8*)(a1 + kt * 32);
#pragma unroll
    for (int nt = 0; nt < 8; ++nt) {
      f16x8 bf = *(const f16x8*)(Bs + (nt * ktiles + kt) * 512 + lane * 8);
      acc[0][nt] = __builtin_amdgcn_mfma_f32_16x16x32_f16(af0, bf, acc[0][nt], 0, 0, 0);
      acc[1][nt] = __builtin_amdgcn_mfma_f32_16x16x32_f16(af1, bf, acc[1][nt], 0, 0, 0);
    }
  }
#pragma unroll
  for (int m = 0; m < 2; ++m) {
    const int crow0 = mw * 32 + m * 16 + quad * 4;
#pragma unroll
    for (int nt = 0; nt < 8; ++nt) {
      const int col = ng * 128 + nt * 16 + r;
      const float b = bias[col];
#pragma unroll
      for (int i = 0; i < 4; ++i)
        Cb[(size_t)(crow0 + i) * N + col] = f2h_bits(acc[m][nt][i] + b);
    }
  }
}

// ---------------------------------------------------------------------------
// QKVS GEMM with SPLIT OUTPUT: N=512 fixed. ng0 -> q (fp16 qsh[row][0..127]),
// ng1/ng2 -> k|v (fp8 kvb[row][0..255]), ng3 -> skip (fp16 qsh[row][128..255]).
// Halves the attn gather bytes (the r11-r14 137MB/3.2TB/s floor).
// ---------------------------------------------------------------------------
__global__ __launch_bounds__(512) void gemm_qkv(
    const unsigned short* __restrict__ A,
    const unsigned short* __restrict__ Bp, const float* __restrict__ bias,
    unsigned short* __restrict__ qsh, unsigned char* __restrict__ kvb, int M)
{
  __shared__ unsigned short Bs[16384];   // ktiles=4 -> 32 KB
  const int ngroups = 4;                 // N = 512
  const int mtiles = M >> 5;
  const int ng = blockIdx.x % ngroups;
  const int mb = blockIdx.x / ngroups;
  const int ktiles = 4;                  // K = 128
  const int tid = threadIdx.x;
  const unsigned short* Bsrc = Bp + (size_t)ng * 8 * ktiles * 512;
  for (int i = tid; i < 2048; i += 512)
    *(uint4*)&Bs[i * 8] = *(const uint4*)&Bsrc[i * 8];
  __syncthreads();
  const int w = tid >> 6;
  const int lane = tid & 63;
  const int mw = mb * 8 + w;
  if (mw >= mtiles) return;
  const int r = lane & 15, quad = lane >> 4;
  const unsigned short* a0 = A + (size_t)(mw * 32 + r) * DD + quad * 8;
  const unsigned short* a1 = a0 + (size_t)16 * DD;
  floatx4 acc[2][8];
#pragma unroll
  for (int m = 0; m < 2; ++m)
#pragma unroll
    for (int nt = 0; nt < 8; ++nt) acc[m][nt] = (floatx4){0.f, 0.f, 0.f, 0.f};
#pragma unroll
  for (int kt = 0; kt < 4; ++kt) {
    f16x8 af0 = *(const f16x8*)(a0 + kt * 32);
    f16x8 af1 = *(const f16x8*)(a1 + kt * 32);
#pragma unroll
    for (int nt = 0; nt < 8; ++nt) {
      f16x8 bf = *(const f16x8*)(Bs + (nt * 4 + kt) * 512 + lane * 8);
      acc[0][nt] = __builtin_amdgcn_mfma_f32_16x16x32_f16(af0, bf, acc[0][nt], 0, 0, 0);
      acc[1][nt] = __builtin_amdgcn_mfma_f32_16x16x32_f16(af1, bf, acc[1][nt], 0, 0, 0);
    }
  }
#pragma unroll
  for (int m = 0; m < 2; ++m) {
    const int crow0 = mw * 32 + m * 16 + quad * 4;
#pragma unroll
    for (int nt = 0; nt < 8; ++nt) {
      const int lc = nt * 16 + r;          // 0..127 within group
      const float b = bias[ng * 128 + lc];
      if (ng == 0) {
#pragma unroll
        for (int i = 0; i < 4; ++i)
          qsh[(size_t)(crow0 + i) * 256 + lc] = f2h_bits(acc[m][nt][i] + b);
      } else if (ng == 3) {
#pragma unroll
        for (int i = 0; i < 4; ++i)
          qsh[(size_t)(crow0 + i) * 256 + 128 + lc] = f2h_bits(acc[m][nt][i] + b);
      } else {                             // k (ng1) | v (ng2) -> fp8
#pragma unroll
        for (int i = 0; i < 4; ++i)
          kvb[(size_t)(crow0 + i) * 256 + (ng - 1) * 128 + lc] =
              f2fp8(acc[m][nt][i] + b);
      }
    }
  }
}

// ---------------------------------------------------------------------------
// fp32-A variant (K=64 only, for gi = x @ Wih^T): fuses xcast (r14-proven).
// ---------------------------------------------------------------------------
__global__ __launch_bounds__(512) void gemm_f32a(
    const float* __restrict__ A,
    const unsigned short* __restrict__ Bp, const float* __restrict__ bias,
    unsigned short* __restrict__ Cb, int M, int N)
{
  __shared__ unsigned short Bs[8192];    // K=64 -> ktiles=2 -> 16 KB
  const int ngroups = N >> 7;
  const int mtiles = M >> 5;
  const int ng = blockIdx.x % ngroups;
  const int mb = blockIdx.x / ngroups;
  const int tid = threadIdx.x;
  const unsigned short* Bsrc = Bp + (size_t)ng * 8 * 2 * 512;
  for (int i = tid; i < 1024; i += 512)
    *(uint4*)&Bs[i * 8] = *(const uint4*)&Bsrc[i * 8];
  __syncthreads();
  const int w = tid >> 6;
  const int lane = tid & 63;
  const int mw = mb * 8 + w;
  if (mw >= mtiles) return;
  const int r = lane & 15, quad = lane >> 4;
  const float* a0 = A + (size_t)(mw * 32 + r) * IND + quad * 8;
  const float* a1 = a0 + (size_t)16 * IND;
  floatx4 acc[2][8];
#pragma unroll
  for (int m = 0; m < 2; ++m)
#pragma unroll
    for (int nt = 0; nt < 8; ++nt) acc[m][nt] = (floatx4){0.f, 0.f, 0.f, 0.f};
#pragma unroll
  for (int kt = 0; kt < 2; ++kt) {
    float4 f00 = *(const float4*)(a0 + kt * 32);
    float4 f01 = *(const float4*)(a0 + kt * 32 + 4);
    float4 f10 = *(const float4*)(a1 + kt * 32);
    float4 f11 = *(const float4*)(a1 + kt * 32 + 4);
    f16x8 af0 = (f16x8){(_Float16)f00.x, (_Float16)f00.y, (_Float16)f00.z,
                        (_Float16)f00.w, (_Float16)f01.x, (_Float16)f01.y,
                        (_Float16)f01.z, (_Float16)f01.w};
    f16x8 af1 = (f16x8){(_Float16)f10.x, (_Float16)f10.y, (_Float16)f10.z,
                        (_Float16)f10.w, (_Float16)f11.x, (_Float16)f11.y,
                        (_Float16)f11.z, (_Float16)f11.w};
#pragma unroll
    for (int nt = 0; nt < 8; ++nt) {
      f16x8 bf = *(const f16x8*)(Bs + (nt * 2 + kt) * 512 + lane * 8);
      acc[0][nt] = __builtin_amdgcn_mfma_f32_16x16x32_f16(af0, bf, acc[0][nt], 0, 0, 0);
      acc[1][nt] = __builtin_amdgcn_mfma_f32_16x16x32_f16(af1, bf, acc[1][nt], 0, 0, 0);
    }
  }
#pragma unroll
  for (int m = 0; m < 2; ++m) {
    const int crow0 = mw * 32 + m * 16 + quad * 4;
#pragma unroll
    for (int nt = 0; nt < 8; ++nt) {
      const int col = ng * 128 + nt * 16 + r;
      const float b = bias[col];
#pragma unroll
      for (int i = 0; i < 4; ++i)
        Cb[(size_t)(crow0 + i) * N + col] = f2h_bits(acc[m][nt][i] + b);
    }
  }
}

// ---------------------------------------------------------------------------
// Weight packing: single f16 in MFMA fragment order + fp32 fused conv bias
// ---------------------------------------------------------------------------
#define BIH_N 24576    // (384/16)*(64/32)*512
#define BHH_N 49152    // 24*4*512
#define WCAT_N 131072  // 2*32*4*512
#define BCAT_N 1024

__global__ void pack_weights(
    const float* __restrict__ Wih, const float* __restrict__ Whh,
    const float* __restrict__ Wq, const float* __restrict__ Wk,
    const float* __restrict__ Wv, const float* __restrict__ Ws,
    const float* __restrict__ bq, const float* __restrict__ bk,
    const float* __restrict__ bv, const float* __restrict__ bs,
    unsigned short* __restrict__ BihP, unsigned short* __restrict__ BhhP,
    unsigned short* __restrict__ WcatP, float* __restrict__ bcat)
{
  int gid = blockIdx.x * 256 + threadIdx.x;
  if (gid < BIH_N) {  // K=64, N=384, ktiles=2
    int tile = gid >> 9, lj = gid & 511, lane = lj >> 3, j = lj & 7;
    int k_tile = tile & 1, n_tile = tile >> 1;
    int n = n_tile * 16 + (lane & 15);
    int k = k_tile * 32 + (lane >> 4) * 8 + j;
    BihP[tile * 512 + lane * 8 + j] = f2h_bits(Wih[n * IND + k]);  // B[k][n]=Wih^T
    return;
  }
  gid -= BIH_N;
  if (gid < BHH_N) {  // K=128, N=384, ktiles=4
    int tile = gid >> 9, lj = gid & 511, lane = lj >> 3, j = lj & 7;
    int k_tile = tile & 3, n_tile = tile >> 2;
    int n = n_tile * 16 + (lane & 15);
    int k = k_tile * 32 + (lane >> 4) * 8 + j;
    BhhP[tile * 512 + lane * 8 + j] = f2h_bits(Whh[n * DD + k]);
    return;
  }
  gid -= BHH_N;
  if (gid < WCAT_N) {  // per layer: K=128, N=512, ktiles=4
    int l = gid >> 16, rem = gid & 65535;
    int tile = rem >> 9, lj = rem & 511, lane = lj >> 3, j = lj & 7;
    int k_tile = tile & 3, n_tile = tile >> 2;
    int n = n_tile * 16 + (lane & 15);
    int k = k_tile * 32 + (lane >> 4) * 8 + j;
    const float* W = (n < 128) ? Wq : (n < 256) ? Wk : (n < 384) ? Wv : Ws;
    WcatP[(size_t)l * 65536 + tile * 512 + lane * 8 + j] =
        f2h_bits(W[l * DD * DD + k * DD + (n & 127)]);
    return;
  }
  gid -= WCAT_N;
  if (gid < BCAT_N) {
    int l = gid >> 9, n = gid & 511;
    const float* b = (n < 128) ? bq : (n < 256) ? bk : (n < 384) ? bv : bs;
    bcat[gid] = b[l * DD + (n & 127)];
  }
}

// ---------------------------------------------------------------------------
// Padded CSR build: ONE pass (r12-proven).
// ---------------------------------------------------------------------------
__global__ void csr_fill(const int* __restrict__ ei, const float* __restrict__ ea,
                         int* __restrict__ deg, int2* __restrict__ cse)
{
  int gid = blockIdx.x * 256 + threadIdx.x;
  if (gid >= T_STEPS * EE) return;
  int t = gid / EE, e = gid % EE;
  int src = ei[(size_t)t * 2 * EE + e];
  int dst = ei[(size_t)t * 2 * EE + EE + e];
  int slot = atomicAdd(&deg[t * NN + dst], 1);
  cse[((size_t)t * NN + dst) * CAP + slot] =
      make_int2(src, __float_as_int(ea[(size_t)t * EE + e]));
}

// ---------------------------------------------------------------------------
// GRU gate fusion (all fp16 activations). t0: gh == b_hh exactly (h0=0).
// ---------------------------------------------------------------------------
__global__ __launch_bounds__(256) void gru_gate(
    const unsigned short* __restrict__ gi, const unsigned short* __restrict__ gh,
    const float* __restrict__ b_hh, int t0,
    const unsigned short* __restrict__ hprev, unsigned short* __restrict__ hout)
{
  int idx = blockIdx.x * 256 + threadIdx.x;   // exact NN*DD grid
  int n = idx >> 7, d = idx & 127;
  size_t gb = (size_t)n * G3 + d;
  float ir = h2f(gi[gb]), iz = h2f(gi[gb + DD]), inn = h2f(gi[gb + 2 * DD]);
  float hr, hz, hn, hp;
  if (t0) {
    hr = b_hh[d]; hz = b_hh[DD + d]; hn = b_hh[2 * DD + d]; hp = 0.f;
  } else {
    hr = h2f(gh[gb]); hz = h2f(gh[gb + DD]); hn = h2f(gh[gb + 2 * DD]);
    hp = h2f(hprev[idx]);
  }
  float r = 1.f / (1.f + __expf(-(ir + hr)));
  float z = 1.f / (1.f + __expf(-(iz + hz)));
  float nv = tanhf(inn + r * hn);
  float hnew = (1.f - z) * nv + z * hp;
  hout[idx] = f2h_bits(hnew);
}

// ---------------------------------------------------------------------------
// Fused TransformerConv (d=128): q/skip fp16 (streamed), k/v fp8 e4m3
// (gathered; 256B/edge vs 512B in r14 -> attacks the measured 137MB/3.2TB/s
// gather floor). r12-proven 4-edge body, padded CSR, XCD swizzle.
// ---------------------------------------------------------------------------
__global__ __launch_bounds__(256) void attn_conv(
    const unsigned short* __restrict__ qsh,   // [T][NN][256] fp16 q|skip
    const unsigned char* __restrict__ kvb,    // [T][NN][256] fp8 k|v
    const int* __restrict__ deg4,     // [T][NN]
    const int2* __restrict__ cse4,    // [T][NN][CAP]
    const float* __restrict__ We,     // [128] fp32
    unsigned short* __restrict__ hoh) // [T][NN][128] fp16 out
{
  const int bid = blockIdx.x;
  const int xc = bid & 7, jb = bid >> 3;
  const int t = xc >> 1;
  const int blk = jb * 2 + (xc & 1);          // 0..2499 within t
  const unsigned short* qs = qsh + (size_t)t * NN * 256;
  const unsigned char* kv = kvb + (size_t)t * NN * 256;
  const int lane = threadIdx.x & 63;
  const int w = threadIdx.x >> 6;             // 4 waves/block
  const int hlf = lane >> 5;
  const int es = (lane >> 3) & 3;             // 4 edge slots
  const int fg = lane & 7;                    // 8 feature groups
  const int node = blk * 8 + w * 2 + hlf;     // exact 20000 per t
  const int f0 = fg * 16;
  const float scale = 0.08838834764831845f;   // 1/sqrt(128)

  union U16 { uint4 u[2]; half2v h[8]; };
  U16 q;
  {
    const uint4* p = (const uint4*)(qs + (size_t)node * 256 + f0);
    q.u[0] = p[0]; q.u[1] = p[1];
  }
  half2v we2[8];
  {
    const float4* wp = (const float4*)&We[f0];
    float4 w0 = wp[0], w1 = wp[1], w2 = wp[2], w3 = wp[3];
    we2[0] = (half2v){(_Float16)w0.x, (_Float16)w0.y};
    we2[1] = (half2v){(_Float16)w0.z, (_Float16)w0.w};
    we2[2] = (half2v){(_Float16)w1.x, (_Float16)w1.y};
    we2[3] = (half2v){(_Float16)w1.z, (_Float16)w1.w};
    we2[4] = (half2v){(_Float16)w2.x, (_Float16)w2.y};
    we2[5] = (half2v){(_Float16)w2.z, (_Float16)w2.w};
    we2[6] = (half2v){(_Float16)w3.x, (_Float16)w3.y};
    we2[7] = (half2v){(_Float16)w3.z, (_Float16)w3.w};
  }
  float qwe = 0.f;
#pragma unroll
  for (int j = 0; j < 8; ++j) {
#if __has_builtin(__builtin_amdgcn_fdot2)
    qwe = __builtin_amdgcn_fdot2(q.h[j], we2[j], qwe, false);
#else
    qwe = fmaf((float)q.h[j].x, (float)we2[j].x, qwe);
    qwe = fmaf((float)q.h[j].y, (float)we2[j].y, qwe);
#endif
  }
  qwe += __shfl_xor(qwe, 1); qwe += __shfl_xor(qwe, 2); qwe += __shfl_xor(qwe, 4);

  const int dg = deg4[t * NN + node];
  const int2* cbase = cse4 + ((size_t)t * NN + node) * CAP;
  float l_lane = 0.f, sA_lane = 0.f;
  half2v acc2[8];
#pragma unroll
  for (int i = 0; i < 8; ++i) acc2[i] = (half2v){(_Float16)0.f, (_Float16)0.f};

  for (int base = 0; base < dg; base += 4) {
    const int eidx = base + es;
    const bool valid = eidx < dg;
    int2 se = valid ? cbase[eidx] : make_int2(0, 0);
    const float a = __int_as_float(se.y);
    union KB { uint4 u; unsigned char b[16]; } kb;
    kb.u = *(const uint4*)(kv + (size_t)se.x * 256 + f0);
    half2v kh[8];
#pragma unroll
    for (int j = 0; j < 8; ++j)
      kh[j] = (half2v){fp82h(kb.b[2 * j]), fp82h(kb.b[2 * j + 1])};
    float p = 0.f;
#pragma unroll
    for (int j = 0; j < 8; ++j) {
#if __has_builtin(__builtin_amdgcn_fdot2)
      p = __builtin_amdgcn_fdot2(q.h[j], kh[j], p, false);
#else
      p = fmaf((float)q.h[j].x, (float)kh[j].x, p);
      p = fmaf((float)q.h[j].y, (float)kh[j].y, p);
#endif
    }
    p += __shfl_xor(p, 1); p += __shfl_xor(p, 2); p += __shfl_xor(p, 4);
    const float ex = valid ? __expf((p + a * qwe) * scale) : 0.f;
    l_lane += ex;
    sA_lane = fmaf(ex, a, sA_lane);
    const _Float16 exh = (_Float16)ex;
    const half2v ex2 = (half2v){exh, exh};
    union KB vb;
    vb.u = *(const uint4*)(kv + (size_t)se.x * 256 + 128 + f0);
#pragma unroll
    for (int j = 0; j < 8; ++j) {
      half2v vh = (half2v){fp82h(vb.b[2 * j]), fp82h(vb.b[2 * j + 1])};
      acc2[j] = ex2 * vh + acc2[j];   // v_pk_fma_f16
    }
  }
  // reductions over the 4 edge-slots (xor 8,16 stay within the 32-lane half)
  l_lane += __shfl_xor(l_lane, 8);  l_lane += __shfl_xor(l_lane, 16);
  sA_lane += __shfl_xor(sA_lane, 8); sA_lane += __shfl_xor(sA_lane, 16);
#pragma unroll
  for (int i = 0; i < 8; ++i) {
    acc2[i] = acc2[i] + shfl_xor_h2(acc2[i], 8);
    acc2[i] = acc2[i] + shfl_xor_h2(acc2[i], 16);
  }
  if (es != 0) return;
  const float inv = 1.f / (l_lane + 1e-16f);
  const float sAi = sA_lane * inv;
  U16 sk;
  {
    const uint4* p = (const uint4*)(qs + (size_t)node * 256 + 128 + f0);
    sk.u[0] = p[0]; sk.u[1] = p[1];
  }
  float wf[16];
  {
    const float4* wp = (const float4*)&We[f0];
#pragma unroll
    for (int j = 0; j < 4; ++j) *(float4*)&wf[4 * j] = wp[j];
  }
  U16 outp;
#pragma unroll
  for (int j = 0; j < 8; ++j) {
    float oa = fmaf((float)acc2[j].x, inv, fmaf(sAi, wf[2 * j],     (float)sk.h[j].x));
    float ob = fmaf((float)acc2[j].y, inv, fmaf(sAi, wf[2 * j + 1], (float)sk.h[j].y));
    oa = (oa > 0.f) ? oa : 0.01f * oa;    // leaky_relu
    ob = (ob > 0.f) ? ob : 0.01f * ob;
    outp.h[j] = (half2v){(_Float16)oa, (_Float16)ob};
  }
  unsigned short* dst = hoh + ((size_t)t * NN + node) * DD + f0;
  *(uint4*)(dst + 0) = outp.u[0];
  *(uint4*)(dst + 8) = outp.u[1];
}

// ---------------------------------------------------------------------------
// Output conv projections with fused mean-over-T (reads hoh fp16 directly)
// ---------------------------------------------------------------------------
__global__ __launch_bounds__(256) void out_proj(
    const unsigned short* __restrict__ hoh,   // [T][NN][128] fp16
    const float* __restrict__ Wq, const float* __restrict__ Wk,
    const float* __restrict__ Wv, const float* __restrict__ Ws,
    const float* __restrict__ bq, const float* __restrict__ bk,
    const float* __restrict__ bv, const float* __restrict__ bs,
    float* __restrict__ q1, float* __restrict__ k1,
    float* __restrict__ v1, float* __restrict__ s1)
{
  const int wv = (blockIdx.x * 256 + threadIdx.x) >> 6;
  const int lane = threadIdx.x & 63;
  if (wv >= NN) return;
  float hx = 0.f, hy = 0.f;
#pragma unroll
  for (int t = 0; t < T_STEPS; ++t) {
    union { unsigned u; half2v h; } c;
    c.u = *(const unsigned*)&hoh[((size_t)t * NN + wv) * DD + 2 * lane];
    hx += (float)c.h.x;
    hy += (float)c.h.y;
  }
  hx *= 0.25f; hy *= 0.25f;
  float pq = hx * Wq[2 * lane] + hy * Wq[2 * lane + 1];
  float pk = hx * Wk[2 * lane] + hy * Wk[2 * lane + 1];
  float pv = hx * Wv[2 * lane] + hy * Wv[2 * lane + 1];
  float ps = hx * Ws[2 * lane] + hy * Ws[2 * lane + 1];
#pragma unroll
  for (int o = 1; o < 64; o <<= 1) {
    pq += __shfl_xor(pq, o); pk += __shfl_xor(pk, o);
    pv += __shfl_xor(pv, o); ps += __shfl_xor(ps, o);
  }
  if (lane == 0) {
    q1[wv] = pq + bq[0]; k1[wv] = pk + bk[0];
    v1[wv] = pv + bv[0]; s1[wv] = ps + bs[0];
  }
}

__global__ void out_attn(
    const float* __restrict__ q1, const float* __restrict__ k1,
    const float* __restrict__ v1, const float* __restrict__ s1,
    const int* __restrict__ deg, const int2* __restrict__ cse,
    const float* __restrict__ We, float* __restrict__ out)
{
  int n = blockIdx.x * 256 + threadIdx.x;
  if (n >= NN) return;
  const float we = We[0];
  const float q = q1[n];
  const int dg = deg[n];
  const int2* cbase = cse + (size_t)n * CAP;
  float m = -INFINITY;
  for (int e = 0; e < dg; ++e) {
    int2 se = cbase[e];
    float al = q * (k1[se.x] + __int_as_float(se.y) * we);
    m = fmaxf(m, al);
  }
  float l = 0.f, acc = 0.f;
  for (int e = 0; e < dg; ++e) {
    int2 se = cbase[e];
    float ca = __int_as_float(se.y);
    float al = q * (k1[se.x] + ca * we);
    float ex = __expf(al - m);
    l += ex;
    acc += ex * (v1[se.x] + ca * we);
  }
  out[n] = acc / (l + 1e-16f) + s1[n];
}

// ---------------------------------------------------------------------------
extern "C" void kernel_launch(void* const* d_in, const int* in_sizes, int n_in,
                              void* d_out, int out_size, void* d_ws, size_t ws_size,
                              hipStream_t stream)
{
  const float* x_seq = (const float*)d_in[0];
  const int*   ei    = (const int*)  d_in[1];
  const float* ea    = (const float*)d_in[2];
  const float* W_ih  = (const float*)d_in[3];
  const float* W_hh  = (const float*)d_in[4];
  const float* b_ih  = (const float*)d_in[5];
  const float* b_hh  = (const float*)d_in[6];
  const float* cWq   = (const float*)d_in[7];
  const float* cbq   = (const float*)d_in[8];
  const float* cWk   = (const float*)d_in[9];
  const float* cbk   = (const float*)d_in[10];
  const float* cWv   = (const float*)d_in[11];
  const float* cbv   = (const float*)d_in[12];
  const float* cWe   = (const float*)d_in[13];
  const float* cWs   = (const float*)d_in[14];
  const float* cbs   = (const float*)d_in[15];
  const float* oWq   = (const float*)d_in[16];
  const float* obq   = (const float*)d_in[17];
  const float* oWk   = (const float*)d_in[18];
  const float* obk   = (const float*)d_in[19];
  const float* oWv   = (const float*)d_in[20];
  const float* obv   = (const float*)d_in[21];
  const float* oWe   = (const float*)d_in[22];
  const float* oWs   = (const float*)d_in[23];
  const float* obs   = (const float*)d_in[24];
  float* out = (float*)d_out;

  char* ws = (char*)d_ws;
  size_t off = 0;
  auto alloc = [&](size_t bytes) -> char* {
    char* p = ws + off;
    off += (bytes + 255) & ~(size_t)255;
    return p;
  };
  // ---- total ~145 MB (<186 MB proven r2; r3's 289 MB aborted) ----
  unsigned short* BihP  = (unsigned short*)alloc((size_t)BIH_N * 2);
  unsigned short* BhhP  = (unsigned short*)alloc((size_t)BHH_N * 2);
  unsigned short* WcatP = (unsigned short*)alloc((size_t)WCAT_N * 2);
  float* fbcat = (float*)alloc((size_t)BCAT_N * 4);
  unsigned short* hall  = (unsigned short*)alloc((size_t)T_STEPS * NN * DD * 2);
  int*   iDeg  = (int*)  alloc((size_t)T_STEPS * NN * 4);     // zero-init
  int2*  iSE   = (int2*) alloc((size_t)T_STEPS * NN * CAP * 8);  // padded CSR
  float* fQ1   = (float*)alloc((size_t)NN * 4);
  float* fK1   = (float*)alloc((size_t)NN * 4);
  float* fV1   = (float*)alloc((size_t)NN * 4);
  float* fS1   = (float*)alloc((size_t)NN * 4);
  // union: GRU phase gi4 [4NN*G3 fp16 = 61.4 MB] + gh [NN*G3 fp16 = 15.4 MB];
  //        conv phase qsh [4NN*256 fp16 = 41 MB] + kvb [4NN*256 u8 = 20.5 MB]
  //                   + hoh [4NN*128 fp16 = 20.5 MB] = 82 MB
  size_t uniOff = off;
  unsigned short* gi4h = (unsigned short*)(ws + uniOff);
  unsigned short* ghh  = (unsigned short*)(ws + uniOff + (size_t)4 * NN * G3 * 2);
  unsigned short* qsh  = (unsigned short*)(ws + uniOff);
  unsigned char*  kvb  = (unsigned char*)(ws + uniOff + (size_t)T_STEPS * NN * 256 * 2);
  unsigned short* hoh  = (unsigned short*)(ws + uniOff + (size_t)T_STEPS * NN * 256 * 3);
  (void)ws_size; (void)in_sizes; (void)n_in; (void)out_size;

  auto gemm = [&](const unsigned short* A, const unsigned short* Bp,
                  const float* bias, unsigned short* Cb, int M, int N, int K) {
    int blocks = (((M >> 5) + 7) >> 3) * (N >> 7);
    gemm_f16<<<blocks, 512, 0, stream>>>(A, Bp, bias, Cb, M, N, K);
  };

  // weights + padded CSR (single pass)
  pack_weights<<<(BIH_N + BHH_N + WCAT_N + BCAT_N + 255) / 256, 256, 0,
                 stream>>>(W_ih, W_hh, cWq, cWk, cWv, cWs, cbq, cbk, cbv, cbs,
                           BihP, BhhP, WcatP, fbcat);
  hipMemsetAsync(iDeg, 0, (size_t)T_STEPS * NN * 4, stream);
  csr_fill<<<(T_STEPS * EE) / 256, 256, 0, stream>>>(ei, ea, iDeg, iSE);

  // GRU: gi for ALL t in one fp32-A GEMM (xcast fused); gh sequential
  {
    int blocks = ((((T_STEPS * NN) >> 5) + 7) >> 3) * (G3 >> 7);
    gemm_f32a<<<blocks, 512, 0, stream>>>(x_seq, BihP, b_ih, gi4h,
                                          T_STEPS * NN, G3);
  }
  for (int t = 0; t < T_STEPS; ++t) {
    const unsigned short* hprev = hall + (size_t)(t - 1) * NN * DD;  // unused t=0
    if (t > 0) gemm(hprev, BhhP, b_hh, ghh, NN, G3, DD);
    gru_gate<<<(NN * DD) / 256, 256, 0, stream>>>(
        gi4h + (size_t)t * NN * G3, ghh, b_hh, (t == 0) ? 1 : 0,
        (t == 0) ? hall : hprev, hall + (size_t)t * NN * DD);
  }

  const int ATTN_BLOCKS = (NN / 8) * T_STEPS;   // 10000, 1D XCD-swizzled
  const int QKV_BLOCKS = (((T_STEPS * NN) >> 5) + 7) >> 3;

  // Layer 1: h (fp16) -> qsh/kvb split ; attn -> hoh
  gemm_qkv<<<QKV_BLOCKS * 4, 512, 0, stream>>>(hall, WcatP, fbcat, qsh, kvb,
                                               T_STEPS * NN);
  attn_conv<<<ATTN_BLOCKS, 256, 0, stream>>>(qsh, kvb, iDeg, iSE, cWe, hoh);

  // Layer 2: hoh -> qsh/kvb ; attn -> hoh (overwrite)
  gemm_qkv<<<QKV_BLOCKS * 4, 512, 0, stream>>>(hoh, WcatP + (size_t)65536,
                                               fbcat + QS, qsh, kvb,
                                               T_STEPS * NN);
  attn_conv<<<ATTN_BLOCKS, 256, 0, stream>>>(qsh, kvb, iDeg, iSE, cWe + DD, hoh);

  // output conv (d=1) on t=3 graph; mean-over-T fused into out_proj
  out_proj<<<(NN * 64) / 256, 256, 0, stream>>>(
      hoh, oWq, oWk, oWv, oWs, obq, obk, obv, obs, fQ1, fK1, fV1, fS1);
  out_attn<<<(NN + 255) / 256, 256, 0, stream>>>(
      fQ1, fK1, fV1, fS1, iDeg + 3 * NN, iSE + (size_t)3 * NN * CAP, oWe, out);
}

// Round 16
// 411.472 us; speedup vs baseline: 1.5699x; 1.5699x over previous
//
#include <hip/hip_runtime.h>
#include <math.h>

#define T_STEPS 4
#define NN 20000
#define EE 160000
#define IND 64
#define DD 128
#define G3 384     // 3*D (GRU gates)
#define QS 512     // q|k|v|skip fused width
#define CAP 48     // padded-CSR capacity (max degree ~24; P(>=48) ~ 1e-25)

typedef _Float16 f16x8 __attribute__((ext_vector_type(8)));
typedef _Float16 half2v __attribute__((ext_vector_type(2)));
typedef float floatx4 __attribute__((ext_vector_type(4)));

// ---------------------------------------------------------------------------
// fp16 / bf8(e5m2) helpers.  e5m2 == truncated fp16: decode is byte<<8
// (compiles to v_perm_b32) — r15's e4m3 library decode was ~60 VALU/elem
// and made attn 94% VALU-bound (170 µs). Encode: f16 RNE + round-to-e5m2.
// ---------------------------------------------------------------------------
__device__ inline unsigned short f2h_bits(float x) {
  union { _Float16 h; unsigned short s; } u;
  u.h = (_Float16)x;   // v_cvt_f16_f32 (RNE)
  return u.s;
}
__device__ inline float h2f(unsigned short s) {
  union { unsigned short s; _Float16 h; } u;
  u.s = s;
  return (float)u.h;
}
__device__ inline half2v shfl_xor_h2(half2v v, int m) {
  union { half2v h; int i; } u; u.h = v;
  u.i = __shfl_xor(u.i, m);
  return u.h;
}
__device__ inline unsigned char f2bf8(float x) {   // OCP e5m2, RNE
  unsigned short h = f2h_bits(x);
  unsigned short r = h + 0x7f + ((h >> 8) & 1);    // round mantissa bits 0..7
  return (unsigned char)(r >> 8);
}
__device__ inline half2v bf8x2_lo(unsigned wd) {   // bytes 0,1 -> half2
  unsigned v = ((wd << 8) & 0x0000FF00u) | ((wd << 16) & 0xFF000000u);
  union { unsigned u; half2v h; } c; c.u = v; return c.h;
}
__device__ inline half2v bf8x2_hi(unsigned wd) {   // bytes 2,3 -> half2
  unsigned v = ((wd >> 8) & 0x0000FF00u) | (wd & 0xFF000000u);
  union { unsigned u; half2v h; } c; c.u = v; return c.h;
}

// ---------------------------------------------------------------------------
// f16 MFMA GEMM, LDS-staged single-f16 B: C = A x B + bias, fp16 out.
// Block = 512 thr (8 waves) sharing one 128-col group; B (<=32KB) staged
// once (r9-proven). 32-row wave tile; DO NOT enlarge (r6 spill).
// ---------------------------------------------------------------------------
__global__ __launch_bounds__(512) void gemm_f16(
    const unsigned short* __restrict__ A,
    const unsigned short* __restrict__ Bp, const float* __restrict__ bias,
    unsigned short* __restrict__ Cb, int M, int N, int K)
{
  __shared__ unsigned short Bs[16384];   // 32 KB (max ktiles=4)
  const int ngroups = N >> 7;
  const int mtiles = M >> 5;
  const int ng = blockIdx.x % ngroups;
  const int mb = blockIdx.x / ngroups;
  const int ktiles = K >> 5;
  const int tid = threadIdx.x;
  const unsigned short* Bsrc = Bp + (size_t)ng * 8 * ktiles * 512;
  const int nchunk = ktiles * 8 * 64;   // 16B chunks
  for (int i = tid; i < nchunk; i += 512)
    *(uint4*)&Bs[i * 8] = *(const uint4*)&Bsrc[i * 8];
  __syncthreads();
  const int w = tid >> 6;
  const int lane = tid & 63;
  const int mw = mb * 8 + w;
  if (mw >= mtiles) return;
  const int r = lane & 15, quad = lane >> 4;
  const unsigned short* a0 = A + (size_t)(mw * 32 + r) * K + quad * 8;
  const unsigned short* a1 = a0 + (size_t)16 * K;
  floatx4 acc[2][8];
#pragma unroll
  for (int m = 0; m < 2; ++m)
#pragma unroll
    for (int nt = 0; nt < 8; ++nt) acc[m][nt] = (floatx4){0.f, 0.f, 0.f, 0.f};
  for (int kt = 0; kt < ktiles; ++kt) {
    f16x8 af0 = *(const f16x8*)(a0 + kt * 32);
    f16x8 af1 = *(const f16x8*)(a1 + kt * 32);
#pragma unroll
    for (int nt = 0; nt < 8; ++nt) {
      f16x8 bf = *(const f16x8*)(Bs + (nt * ktiles + kt) * 512 + lane * 8);
      acc[0][nt] = __builtin_amdgcn_mfma_f32_16x16x32_f16(af0, bf, acc[0][nt], 0, 0, 0);
      acc[1][nt] = __builtin_amdgcn_mfma_f32_16x16x32_f16(af1, bf, acc[1][nt], 0, 0, 0);
    }
  }
#pragma unroll
  for (int m = 0; m < 2; ++m) {
    const int crow0 = mw * 32 + m * 16 + quad * 4;
#pragma unroll
    for (int nt = 0; nt < 8; ++nt) {
      const int col = ng * 128 + nt * 16 + r;
      const float b = bias[col];
#pragma unroll
      for (int i = 0; i < 4; ++i)
        Cb[(size_t)(crow0 + i) * N + col] = f2h_bits(acc[m][nt][i] + b);
    }
  }
}

// ---------------------------------------------------------------------------
// QKVS GEMM with SPLIT OUTPUT: ng0 -> q (fp16 qsh[row][0..127]),
// ng1/ng2 -> k|v (bf8-e5m2 kvb[row][0..255]), ng3 -> skip (qsh[row][128..255]).
// Halves the attn gather bytes (r15-verified: FETCH 137 -> 69 MB).
// ---------------------------------------------------------------------------
__global__ __launch_bounds__(512) void gemm_qkv(
    const unsigned short* __restrict__ A,
    const unsigned short* __restrict__ Bp, const float* __restrict__ bias,
    unsigned short* __restrict__ qsh, unsigned char* __restrict__ kvb, int M)
{
  __shared__ unsigned short Bs[16384];   // ktiles=4 -> 32 KB
  const int ngroups = 4;                 // N = 512
  const int mtiles = M >> 5;
  const int ng = blockIdx.x % ngroups;
  const int mb = blockIdx.x / ngroups;
  const int tid = threadIdx.x;
  const unsigned short* Bsrc = Bp + (size_t)ng * 8 * 4 * 512;
  for (int i = tid; i < 2048; i += 512)
    *(uint4*)&Bs[i * 8] = *(const uint4*)&Bsrc[i * 8];
  __syncthreads();
  const int w = tid >> 6;
  const int lane = tid & 63;
  const int mw = mb * 8 + w;
  if (mw >= mtiles) return;
  const int r = lane & 15, quad = lane >> 4;
  const unsigned short* a0 = A + (size_t)(mw * 32 + r) * DD + quad * 8;
  const unsigned short* a1 = a0 + (size_t)16 * DD;
  floatx4 acc[2][8];
#pragma unroll
  for (int m = 0; m < 2; ++m)
#pragma unroll
    for (int nt = 0; nt < 8; ++nt) acc[m][nt] = (floatx4){0.f, 0.f, 0.f, 0.f};
#pragma unroll
  for (int kt = 0; kt < 4; ++kt) {
    f16x8 af0 = *(const f16x8*)(a0 + kt * 32);
    f16x8 af1 = *(const f16x8*)(a1 + kt * 32);
#pragma unroll
    for (int nt = 0; nt < 8; ++nt) {
      f16x8 bf = *(const f16x8*)(Bs + (nt * 4 + kt) * 512 + lane * 8);
      acc[0][nt] = __builtin_amdgcn_mfma_f32_16x16x32_f16(af0, bf, acc[0][nt], 0, 0, 0);
      acc[1][nt] = __builtin_amdgcn_mfma_f32_16x16x32_f16(af1, bf, acc[1][nt], 0, 0, 0);
    }
  }
#pragma unroll
  for (int m = 0; m < 2; ++m) {
    const int crow0 = mw * 32 + m * 16 + quad * 4;
#pragma unroll
    for (int nt = 0; nt < 8; ++nt) {
      const int lc = nt * 16 + r;          // 0..127 within group
      const float b = bias[ng * 128 + lc];
      if (ng == 0) {
#pragma unroll
        for (int i = 0; i < 4; ++i)
          qsh[(size_t)(crow0 + i) * 256 + lc] = f2h_bits(acc[m][nt][i] + b);
      } else if (ng == 3) {
#pragma unroll
        for (int i = 0; i < 4; ++i)
          qsh[(size_t)(crow0 + i) * 256 + 128 + lc] = f2h_bits(acc[m][nt][i] + b);
      } else {                             // k (ng1) | v (ng2) -> bf8 e5m2
#pragma unroll
        for (int i = 0; i < 4; ++i)
          kvb[(size_t)(crow0 + i) * 256 + (ng - 1) * 128 + lc] =
              f2bf8(acc[m][nt][i] + b);
      }
    }
  }
}

// ---------------------------------------------------------------------------
// fp32-A variant (K=64 only, for gi = x @ Wih^T): fuses xcast (r14-proven).
// ---------------------------------------------------------------------------
__global__ __launch_bounds__(512) void gemm_f32a(
    const float* __restrict__ A,
    const unsigned short* __restrict__ Bp, const float* __restrict__ bias,
    unsigned short* __restrict__ Cb, int M, int N)
{
  __shared__ unsigned short Bs[8192];    // K=64 -> ktiles=2 -> 16 KB
  const int ngroups = N >> 7;
  const int mtiles = M >> 5;
  const int ng = blockIdx.x % ngroups;
  const int mb = blockIdx.x / ngroups;
  const int tid = threadIdx.x;
  const unsigned short* Bsrc = Bp + (size_t)ng * 8 * 2 * 512;
  for (int i = tid; i < 1024; i += 512)
    *(uint4*)&Bs[i * 8] = *(const uint4*)&Bsrc[i * 8];
  __syncthreads();
  const int w = tid >> 6;
  const int lane = tid & 63;
  const int mw = mb * 8 + w;
  if (mw >= mtiles) return;
  const int r = lane & 15, quad = lane >> 4;
  const float* a0 = A + (size_t)(mw * 32 + r) * IND + quad * 8;
  const float* a1 = a0 + (size_t)16 * IND;
  floatx4 acc[2][8];
#pragma unroll
  for (int m = 0; m < 2; ++m)
#pragma unroll
    for (int nt = 0; nt < 8; ++nt) acc[m][nt] = (floatx4){0.f, 0.f, 0.f, 0.f};
#pragma unroll
  for (int kt = 0; kt < 2; ++kt) {
    float4 f00 = *(const float4*)(a0 + kt * 32);
    float4 f01 = *(const float4*)(a0 + kt * 32 + 4);
    float4 f10 = *(const float4*)(a1 + kt * 32);
    float4 f11 = *(const float4*)(a1 + kt * 32 + 4);
    f16x8 af0 = (f16x8){(_Float16)f00.x, (_Float16)f00.y, (_Float16)f00.z,
                        (_Float16)f00.w, (_Float16)f01.x, (_Float16)f01.y,
                        (_Float16)f01.z, (_Float16)f01.w};
    f16x8 af1 = (f16x8){(_Float16)f10.x, (_Float16)f10.y, (_Float16)f10.z,
                        (_Float16)f10.w, (_Float16)f11.x, (_Float16)f11.y,
                        (_Float16)f11.z, (_Float16)f11.w};
#pragma unroll
    for (int nt = 0; nt < 8; ++nt) {
      f16x8 bf = *(const f16x8*)(Bs + (nt * 2 + kt) * 512 + lane * 8);
      acc[0][nt] = __builtin_amdgcn_mfma_f32_16x16x32_f16(af0, bf, acc[0][nt], 0, 0, 0);
      acc[1][nt] = __builtin_amdgcn_mfma_f32_16x16x32_f16(af1, bf, acc[1][nt], 0, 0, 0);
    }
  }
#pragma unroll
  for (int m = 0; m < 2; ++m) {
    const int crow0 = mw * 32 + m * 16 + quad * 4;
#pragma unroll
    for (int nt = 0; nt < 8; ++nt) {
      const int col = ng * 128 + nt * 16 + r;
      const float b = bias[col];
#pragma unroll
      for (int i = 0; i < 4; ++i)
        Cb[(size_t)(crow0 + i) * N + col] = f2h_bits(acc[m][nt][i] + b);
    }
  }
}

// ---------------------------------------------------------------------------
// Weight packing: single f16 in MFMA fragment order + fp32 fused conv bias
// ---------------------------------------------------------------------------
#define BIH_N 24576    // (384/16)*(64/32)*512
#define BHH_N 49152    // 24*4*512
#define WCAT_N 131072  // 2*32*4*512
#define BCAT_N 1024

__global__ void pack_weights(
    const float* __restrict__ Wih, const float* __restrict__ Whh,
    const float* __restrict__ Wq, const float* __restrict__ Wk,
    const float* __restrict__ Wv, const float* __restrict__ Ws,
    const float* __restrict__ bq, const float* __restrict__ bk,
    const float* __restrict__ bv, const float* __restrict__ bs,
    unsigned short* __restrict__ BihP, unsigned short* __restrict__ BhhP,
    unsigned short* __restrict__ WcatP, float* __restrict__ bcat)
{
  int gid = blockIdx.x * 256 + threadIdx.x;
  if (gid < BIH_N) {  // K=64, N=384, ktiles=2
    int tile = gid >> 9, lj = gid & 511, lane = lj >> 3, j = lj & 7;
    int k_tile = tile & 1, n_tile = tile >> 1;
    int n = n_tile * 16 + (lane & 15);
    int k = k_tile * 32 + (lane >> 4) * 8 + j;
    BihP[tile * 512 + lane * 8 + j] = f2h_bits(Wih[n * IND + k]);  // B[k][n]=Wih^T
    return;
  }
  gid -= BIH_N;
  if (gid < BHH_N) {  // K=128, N=384, ktiles=4
    int tile = gid >> 9, lj = gid & 511, lane = lj >> 3, j = lj & 7;
    int k_tile = tile & 3, n_tile = tile >> 2;
    int n = n_tile * 16 + (lane & 15);
    int k = k_tile * 32 + (lane >> 4) * 8 + j;
    BhhP[tile * 512 + lane * 8 + j] = f2h_bits(Whh[n * DD + k]);
    return;
  }
  gid -= BHH_N;
  if (gid < WCAT_N) {  // per layer: K=128, N=512, ktiles=4
    int l = gid >> 16, rem = gid & 65535;
    int tile = rem >> 9, lj = rem & 511, lane = lj >> 3, j = lj & 7;
    int k_tile = tile & 3, n_tile = tile >> 2;
    int n = n_tile * 16 + (lane & 15);
    int k = k_tile * 32 + (lane >> 4) * 8 + j;
    const float* W = (n < 128) ? Wq : (n < 256) ? Wk : (n < 384) ? Wv : Ws;
    WcatP[(size_t)l * 65536 + tile * 512 + lane * 8 + j] =
        f2h_bits(W[l * DD * DD + k * DD + (n & 127)]);
    return;
  }
  gid -= WCAT_N;
  if (gid < BCAT_N) {
    int l = gid >> 9, n = gid & 511;
    const float* b = (n < 128) ? bq : (n < 256) ? bk : (n < 384) ? bv : bs;
    bcat[gid] = b[l * DD + (n & 127)];
  }
}

// ---------------------------------------------------------------------------
// Padded CSR build: ONE pass (r12-proven).
// ---------------------------------------------------------------------------
__global__ void csr_fill(const int* __restrict__ ei, const float* __restrict__ ea,
                         int* __restrict__ deg, int2* __restrict__ cse)
{
  int gid = blockIdx.x * 256 + threadIdx.x;
  if (gid >= T_STEPS * EE) return;
  int t = gid / EE, e = gid % EE;
  int src = ei[(size_t)t * 2 * EE + e];
  int dst = ei[(size_t)t * 2 * EE + EE + e];
  int slot = atomicAdd(&deg[t * NN + dst], 1);
  cse[((size_t)t * NN + dst) * CAP + slot] =
      make_int2(src, __float_as_int(ea[(size_t)t * EE + e]));
}

// ---------------------------------------------------------------------------
// GRU gate fusion (all fp16 activations). t0: gh == b_hh exactly (h0=0).
// ---------------------------------------------------------------------------
__global__ __launch_bounds__(256) void gru_gate(
    const unsigned short* __restrict__ gi, const unsigned short* __restrict__ gh,
    const float* __restrict__ b_hh, int t0,
    const unsigned short* __restrict__ hprev, unsigned short* __restrict__ hout)
{
  int idx = blockIdx.x * 256 + threadIdx.x;   // exact NN*DD grid
  int n = idx >> 7, d = idx & 127;
  size_t gb = (size_t)n * G3 + d;
  float ir = h2f(gi[gb]), iz = h2f(gi[gb + DD]), inn = h2f(gi[gb + 2 * DD]);
  float hr, hz, hn, hp;
  if (t0) {
    hr = b_hh[d]; hz = b_hh[DD + d]; hn = b_hh[2 * DD + d]; hp = 0.f;
  } else {
    hr = h2f(gh[gb]); hz = h2f(gh[gb + DD]); hn = h2f(gh[gb + 2 * DD]);
    hp = h2f(hprev[idx]);
  }
  float r = 1.f / (1.f + __expf(-(ir + hr)));
  float z = 1.f / (1.f + __expf(-(iz + hz)));
  float nv = tanhf(inn + r * hn);
  float hnew = (1.f - z) * nv + z * hp;
  hout[idx] = f2h_bits(hnew);
}

// ---------------------------------------------------------------------------
// Fused TransformerConv (d=128): q/skip fp16 (streamed), k/v bf8-e5m2
// (gathered, 256B/edge; decode = byte<<8 via shifts -> v_perm, ~1 inst per
// 2 elems vs r15's ~60). r12-proven 4-edge body, padded CSR, XCD swizzle.
// ---------------------------------------------------------------------------
__global__ __launch_bounds__(256) void attn_conv(
    const unsigned short* __restrict__ qsh,   // [T][NN][256] fp16 q|skip
    const unsigned char* __restrict__ kvb,    // [T][NN][256] bf8 k|v
    const int* __restrict__ deg4,     // [T][NN]
    const int2* __restrict__ cse4,    // [T][NN][CAP]
    const float* __restrict__ We,     // [128] fp32
    unsigned short* __restrict__ hoh) // [T][NN][128] fp16 out
{
  const int bid = blockIdx.x;
  const int xc = bid & 7, jb = bid >> 3;
  const int t = xc >> 1;
  const int blk = jb * 2 + (xc & 1);          // 0..2499 within t
  const unsigned short* qs = qsh + (size_t)t * NN * 256;
  const unsigned char* kv = kvb + (size_t)t * NN * 256;
  const int lane = threadIdx.x & 63;
  const int w = threadIdx.x >> 6;             // 4 waves/block
  const int hlf = lane >> 5;
  const int es = (lane >> 3) & 3;             // 4 edge slots
  const int fg = lane & 7;                    // 8 feature groups
  const int node = blk * 8 + w * 2 + hlf;     // exact 20000 per t
  const int f0 = fg * 16;
  const float scale = 0.08838834764831845f;   // 1/sqrt(128)

  union U16 { uint4 u[2]; half2v h[8]; };
  U16 q;
  {
    const uint4* p = (const uint4*)(qs + (size_t)node * 256 + f0);
    q.u[0] = p[0]; q.u[1] = p[1];
  }
  half2v we2[8];
  {
    const float4* wp = (const float4*)&We[f0];
    float4 w0 = wp[0], w1 = wp[1], w2 = wp[2], w3 = wp[3];
    we2[0] = (half2v){(_Float16)w0.x, (_Float16)w0.y};
    we2[1] = (half2v){(_Float16)w0.z, (_Float16)w0.w};
    we2[2] = (half2v){(_Float16)w1.x, (_Float16)w1.y};
    we2[3] = (half2v){(_Float16)w1.z, (_Float16)w1.w};
    we2[4] = (half2v){(_Float16)w2.x, (_Float16)w2.y};
    we2[5] = (half2v){(_Float16)w2.z, (_Float16)w2.w};
    we2[6] = (half2v){(_Float16)w3.x, (_Float16)w3.y};
    we2[7] = (half2v){(_Float16)w3.z, (_Float16)w3.w};
  }
  float qwe = 0.f;
#pragma unroll
  for (int j = 0; j < 8; ++j) {
#if __has_builtin(__builtin_amdgcn_fdot2)
    qwe = __builtin_amdgcn_fdot2(q.h[j], we2[j], qwe, false);
#else
    qwe = fmaf((float)q.h[j].x, (float)we2[j].x, qwe);
    qwe = fmaf((float)q.h[j].y, (float)we2[j].y, qwe);
#endif
  }
  qwe += __shfl_xor(qwe, 1); qwe += __shfl_xor(qwe, 2); qwe += __shfl_xor(qwe, 4);

  const int dg = deg4[t * NN + node];
  const int2* cbase = cse4 + ((size_t)t * NN + node) * CAP;
  float l_lane = 0.f, sA_lane = 0.f;
  half2v acc2[8];
#pragma unroll
  for (int i = 0; i < 8; ++i) acc2[i] = (half2v){(_Float16)0.f, (_Float16)0.f};

  for (int base = 0; base < dg; base += 4) {
    const int eidx = base + es;
    const bool valid = eidx < dg;
    int2 se = valid ? cbase[eidx] : make_int2(0, 0);
    const float a = __int_as_float(se.y);
    uint4 kb = *(const uint4*)(kv + (size_t)se.x * 256 + f0);
    half2v kh[8];
    kh[0] = bf8x2_lo(kb.x); kh[1] = bf8x2_hi(kb.x);
    kh[2] = bf8x2_lo(kb.y); kh[3] = bf8x2_hi(kb.y);
    kh[4] = bf8x2_lo(kb.z); kh[5] = bf8x2_hi(kb.z);
    kh[6] = bf8x2_lo(kb.w); kh[7] = bf8x2_hi(kb.w);
    float p = 0.f;
#pragma unroll
    for (int j = 0; j < 8; ++j) {
#if __has_builtin(__builtin_amdgcn_fdot2)
      p = __builtin_amdgcn_fdot2(q.h[j], kh[j], p, false);
#else
      p = fmaf((float)q.h[j].x, (float)kh[j].x, p);
      p = fmaf((float)q.h[j].y, (float)kh[j].y, p);
#endif
    }
    p += __shfl_xor(p, 1); p += __shfl_xor(p, 2); p += __shfl_xor(p, 4);
    const float ex = valid ? __expf((p + a * qwe) * scale) : 0.f;
    l_lane += ex;
    sA_lane = fmaf(ex, a, sA_lane);
    const _Float16 exh = (_Float16)ex;
    const half2v ex2 = (half2v){exh, exh};
    uint4 vb = *(const uint4*)(kv + (size_t)se.x * 256 + 128 + f0);
    half2v vh[8];
    vh[0] = bf8x2_lo(vb.x); vh[1] = bf8x2_hi(vb.x);
    vh[2] = bf8x2_lo(vb.y); vh[3] = bf8x2_hi(vb.y);
    vh[4] = bf8x2_lo(vb.z); vh[5] = bf8x2_hi(vb.z);
    vh[6] = bf8x2_lo(vb.w); vh[7] = bf8x2_hi(vb.w);
#pragma unroll
    for (int j = 0; j < 8; ++j)
      acc2[j] = ex2 * vh[j] + acc2[j];   // v_pk_fma_f16
  }
  // reductions over the 4 edge-slots (xor 8,16 stay within the 32-lane half)
  l_lane += __shfl_xor(l_lane, 8);  l_lane += __shfl_xor(l_lane, 16);
  sA_lane += __shfl_xor(sA_lane, 8); sA_lane += __shfl_xor(sA_lane, 16);
#pragma unroll
  for (int i = 0; i < 8; ++i) {
    acc2[i] = acc2[i] + shfl_xor_h2(acc2[i], 8);
    acc2[i] = acc2[i] + shfl_xor_h2(acc2[i], 16);
  }
  if (es != 0) return;
  const float inv = 1.f / (l_lane + 1e-16f);
  const float sAi = sA_lane * inv;
  U16 sk;
  {
    const uint4* p = (const uint4*)(qs + (size_t)node * 256 + 128 + f0);
    sk.u[0] = p[0]; sk.u[1] = p[1];
  }
  float wf[16];
  {
    const float4* wp = (const float4*)&We[f0];
#pragma unroll
    for (int j = 0; j < 4; ++j) *(float4*)&wf[4 * j] = wp[j];
  }
  U16 outp;
#pragma unroll
  for (int j = 0; j < 8; ++j) {
    float oa = fmaf((float)acc2[j].x, inv, fmaf(sAi, wf[2 * j],     (float)sk.h[j].x));
    float ob = fmaf((float)acc2[j].y, inv, fmaf(sAi, wf[2 * j + 1], (float)sk.h[j].y));
    oa = (oa > 0.f) ? oa : 0.01f * oa;    // leaky_relu
    ob = (ob > 0.f) ? ob : 0.01f * ob;
    outp.h[j] = (half2v){(_Float16)oa, (_Float16)ob};
  }
  unsigned short* dst = hoh + ((size_t)t * NN + node) * DD + f0;
  *(uint4*)(dst + 0) = outp.u[0];
  *(uint4*)(dst + 8) = outp.u[1];
}

// ---------------------------------------------------------------------------
// Output conv projections with fused mean-over-T (reads hoh fp16 directly)
// ---------------------------------------------------------------------------
__global__ __launch_bounds__(256) void out_proj(
    const unsigned short* __restrict__ hoh,   // [T][NN][128] fp16
    const float* __restrict__ Wq, const float* __restrict__ Wk,
    const float* __restrict__ Wv, const float* __restrict__ Ws,
    const float* __restrict__ bq, const float* __restrict__ bk,
    const float* __restrict__ bv, const float* __restrict__ bs,
    float* __restrict__ q1, float* __restrict__ k1,
    float* __restrict__ v1, float* __restrict__ s1)
{
  const int wv = (blockIdx.x * 256 + threadIdx.x) >> 6;
  const int lane = threadIdx.x & 63;
  if (wv >= NN) return;
  float hx = 0.f, hy = 0.f;
#pragma unroll
  for (int t = 0; t < T_STEPS; ++t) {
    union { unsigned u; half2v h; } c;
    c.u = *(const unsigned*)&hoh[((size_t)t * NN + wv) * DD + 2 * lane];
    hx += (float)c.h.x;
    hy += (float)c.h.y;
  }
  hx *= 0.25f; hy *= 0.25f;
  float pq = hx * Wq[2 * lane] + hy * Wq[2 * lane + 1];
  float pk = hx * Wk[2 * lane] + hy * Wk[2 * lane + 1];
  float pv = hx * Wv[2 * lane] + hy * Wv[2 * lane + 1];
  float ps = hx * Ws[2 * lane] + hy * Ws[2 * lane + 1];
#pragma unroll
  for (int o = 1; o < 64; o <<= 1) {
    pq += __shfl_xor(pq, o); pk += __shfl_xor(pk, o);
    pv += __shfl_xor(pv, o); ps += __shfl_xor(ps, o);
  }
  if (lane == 0) {
    q1[wv] = pq + bq[0]; k1[wv] = pk + bk[0];
    v1[wv] = pv + bv[0]; s1[wv] = ps + bs[0];
  }
}

__global__ void out_attn(
    const float* __restrict__ q1, const float* __restrict__ k1,
    const float* __restrict__ v1, const float* __restrict__ s1,
    const int* __restrict__ deg, const int2* __restrict__ cse,
    const float* __restrict__ We, float* __restrict__ out)
{
  int n = blockIdx.x * 256 + threadIdx.x;
  if (n >= NN) return;
  const float we = We[0];
  const float q = q1[n];
  const int dg = deg[n];
  const int2* cbase = cse + (size_t)n * CAP;
  float m = -INFINITY;
  for (int e = 0; e < dg; ++e) {
    int2 se = cbase[e];
    float al = q * (k1[se.x] + __int_as_float(se.y) * we);
    m = fmaxf(m, al);
  }
  float l = 0.f, acc = 0.f;
  for (int e = 0; e < dg; ++e) {
    int2 se = cbase[e];
    float ca = __int_as_float(se.y);
    float al = q * (k1[se.x] + ca * we);
    float ex = __expf(al - m);
    l += ex;
    acc += ex * (v1[se.x] + ca * we);
  }
  out[n] = acc / (l + 1e-16f) + s1[n];
}

// ---------------------------------------------------------------------------
extern "C" void kernel_launch(void* const* d_in, const int* in_sizes, int n_in,
                              void* d_out, int out_size, void* d_ws, size_t ws_size,
                              hipStream_t stream)
{
  const float* x_seq = (const float*)d_in[0];
  const int*   ei    = (const int*)  d_in[1];
  const float* ea    = (const float*)d_in[2];
  const float* W_ih  = (const float*)d_in[3];
  const float* W_hh  = (const float*)d_in[4];
  const float* b_ih  = (const float*)d_in[5];
  const float* b_hh  = (const float*)d_in[6];
  const float* cWq   = (const float*)d_in[7];
  const float* cbq   = (const float*)d_in[8];
  const float* cWk   = (const float*)d_in[9];
  const float* cbk   = (const float*)d_in[10];
  const float* cWv   = (const float*)d_in[11];
  const float* cbv   = (const float*)d_in[12];
  const float* cWe   = (const float*)d_in[13];
  const float* cWs   = (const float*)d_in[14];
  const float* cbs   = (const float*)d_in[15];
  const float* oWq   = (const float*)d_in[16];
  const float* obq   = (const float*)d_in[17];
  const float* oWk   = (const float*)d_in[18];
  const float* obk   = (const float*)d_in[19];
  const float* oWv   = (const float*)d_in[20];
  const float* obv   = (const float*)d_in[21];
  const float* oWe   = (const float*)d_in[22];
  const float* oWs   = (const float*)d_in[23];
  const float* obs   = (const float*)d_in[24];
  float* out = (float*)d_out;

  char* ws = (char*)d_ws;
  size_t off = 0;
  auto alloc = [&](size_t bytes) -> char* {
    char* p = ws + off;
    off += (bytes + 255) & ~(size_t)255;
    return p;
  };
  // ---- total ~145 MB (<186 MB proven r2; r3's 289 MB aborted) ----
  unsigned short* BihP  = (unsigned short*)alloc((size_t)BIH_N * 2);
  unsigned short* BhhP  = (unsigned short*)alloc((size_t)BHH_N * 2);
  unsigned short* WcatP = (unsigned short*)alloc((size_t)WCAT_N * 2);
  float* fbcat = (float*)alloc((size_t)BCAT_N * 4);
  unsigned short* hall  = (unsigned short*)alloc((size_t)T_STEPS * NN * DD * 2);
  int*   iDeg  = (int*)  alloc((size_t)T_STEPS * NN * 4);     // zero-init
  int2*  iSE   = (int2*) alloc((size_t)T_STEPS * NN * CAP * 8);  // padded CSR
  float* fQ1   = (float*)alloc((size_t)NN * 4);
  float* fK1   = (float*)alloc((size_t)NN * 4);
  float* fV1   = (float*)alloc((size_t)NN * 4);
  float* fS1   = (float*)alloc((size_t)NN * 4);
  // union: GRU phase gi4 [4NN*G3 fp16 = 61.4 MB] + gh [NN*G3 fp16 = 15.4 MB];
  //        conv phase qsh [4NN*256 fp16 = 41 MB] + kvb [4NN*256 u8 = 20.5 MB]
  //                   + hoh [4NN*128 fp16 = 20.5 MB] = 82 MB
  size_t uniOff = off;
  unsigned short* gi4h = (unsigned short*)(ws + uniOff);
  unsigned short* ghh  = (unsigned short*)(ws + uniOff + (size_t)4 * NN * G3 * 2);
  unsigned short* qsh  = (unsigned short*)(ws + uniOff);
  unsigned char*  kvb  = (unsigned char*)(ws + uniOff + (size_t)T_STEPS * NN * 256 * 2);
  unsigned short* hoh  = (unsigned short*)(ws + uniOff + (size_t)T_STEPS * NN * 256 * 3);
  (void)ws_size; (void)in_sizes; (void)n_in; (void)out_size;

  auto gemm = [&](const unsigned short* A, const unsigned short* Bp,
                  const float* bias, unsigned short* Cb, int M, int N, int K) {
    int blocks = (((M >> 5) + 7) >> 3) * (N >> 7);
    gemm_f16<<<blocks, 512, 0, stream>>>(A, Bp, bias, Cb, M, N, K);
  };

  // weights + padded CSR (single pass)
  pack_weights<<<(BIH_N + BHH_N + WCAT_N + BCAT_N + 255) / 256, 256, 0,
                 stream>>>(W_ih, W_hh, cWq, cWk, cWv, cWs, cbq, cbk, cbv, cbs,
                           BihP, BhhP, WcatP, fbcat);
  hipMemsetAsync(iDeg, 0, (size_t)T_STEPS * NN * 4, stream);
  csr_fill<<<(T_STEPS * EE) / 256, 256, 0, stream>>>(ei, ea, iDeg, iSE);

  // GRU: gi for ALL t in one fp32-A GEMM (xcast fused); gh sequential
  {
    int blocks = ((((T_STEPS * NN) >> 5) + 7) >> 3) * (G3 >> 7);
    gemm_f32a<<<blocks, 512, 0, stream>>>(x_seq, BihP, b_ih, gi4h,
                                          T_STEPS * NN, G3);
  }
  for (int t = 0; t < T_STEPS; ++t) {
    const unsigned short* hprev = hall + (size_t)(t - 1) * NN * DD;  // unused t=0
    if (t > 0) gemm(hprev, BhhP, b_hh, ghh, NN, G3, DD);
    gru_gate<<<(NN * DD) / 256, 256, 0, stream>>>(
        gi4h + (size_t)t * NN * G3, ghh, b_hh, (t == 0) ? 1 : 0,
        (t == 0) ? hall : hprev, hall + (size_t)t * NN * DD);
  }

  const int ATTN_BLOCKS = (NN / 8) * T_STEPS;   // 10000, 1D XCD-swizzled
  const int QKV_BLOCKS = (((T_STEPS * NN) >> 5) + 7) >> 3;

  // Layer 1: h (fp16) -> qsh/kvb split ; attn -> hoh
  gemm_qkv<<<QKV_BLOCKS * 4, 512, 0, stream>>>(hall, WcatP, fbcat, qsh, kvb,
                                               T_STEPS * NN);
  attn_conv<<<ATTN_BLOCKS, 256, 0, stream>>>(qsh, kvb, iDeg, iSE, cWe, hoh);

  // Layer 2: hoh -> qsh/kvb ; attn -> hoh (overwrite)
  gemm_qkv<<<QKV_BLOCKS * 4, 512, 0, stream>>>(hoh, WcatP + (size_t)65536,
                                               fbcat + QS, qsh, kvb,
                                               T_STEPS * NN);
  attn_conv<<<ATTN_BLOCKS, 256, 0, stream>>>(qsh, kvb, iDeg, iSE, cWe + DD, hoh);

  // output conv (d=1) on t=3 graph; mean-over-T fused into out_proj
  out_proj<<<(NN * 64) / 256, 256, 0, stream>>>(
      hoh, oWq, oWk, oWv, oWs, obq, obk, obv, obs, fQ1, fK1, fV1, fS1);
  out_attn<<<(NN + 255) / 256, 256, 0, stream>>>(
      fQ1, fK1, fV1, fS1, iDeg + 3 * NN, iSE + (size_t)3 * NN * CAP, oWe, out);
}